// Round 5
// baseline (242.281 us; speedup 1.0000x reference)
//
#include <hip/hip_runtime.h>
#include <math.h>

typedef unsigned int  uint;
typedef unsigned short ushort;

// Problem constants
constexpr int NPTS = 30000;
constexpr int CIN  = 128;
constexpr int OC   = 128;   // O
constexpr int NH   = 8;     // heads
constexpr int NS   = 16;    // neighbors
constexpr int DH   = 16;    // O/H
constexpr int OSH  = 16;    // O/SHARE
constexpr float EPSF = 1e-5f;

typedef __attribute__((ext_vector_type(8))) short bf16x8;
typedef __attribute__((ext_vector_type(4))) float f32x4;

__device__ __forceinline__ ushort f2bf(float f) {
    uint u = __float_as_uint(f);
    u += 0x7fff + ((u >> 16) & 1);   // RNE
    return (ushort)(u >> 16);
}
__device__ __forceinline__ void bf2f2(uint u, float& f0, float& f1) {
    f0 = __uint_as_float(u << 16);
    f1 = __uint_as_float(u & 0xffff0000u);
}

// ---------------------------------------------------------------------------
// Kernel 1: QKV projection via bf16 MFMA (16x16x32).
// Block = 128 rows x 128 cols; K=128 in two 64-wide staged halves
// (LDS 36,864 B). A converted fp32->bf16 during staging; B (W) transposed
// into LDS. q output fp32; k,v bf16.
// Fragments (m89/m91/m120): A[m=lane&15][k=quad*8+j]; B[k=quad*8+j][n=lane&15];
// C/D col=lane&15, row=quad*4+reg.
// ---------------------------------------------------------------------------
constexpr int LDK = 72;   // ushort stride for 64-k tiles (144 B, 16B-aligned)

__global__ __launch_bounds__(256) void qkv_mfma(
    const float* __restrict__ x,
    const float* __restrict__ Wq, const float* __restrict__ Wk, const float* __restrict__ Wv,
    const float* __restrict__ bq, const float* __restrict__ bk, const float* __restrict__ bv,
    float* __restrict__ yq, ushort* __restrict__ yk, ushort* __restrict__ yv)
{
    const int mat = blockIdx.y;
    const float* W    = (mat == 0) ? Wq : (mat == 1 ? Wk : Wv);
    const float* bias = (mat == 0) ? bq : (mat == 1 ? bk : bv);

    const int n0 = blockIdx.x * 128;
    const int t  = threadIdx.x;

    __shared__ ushort As[128 * LDK];   // rows x k-half
    __shared__ ushort Bs[128 * LDK];   // cols x k-half (W^T)

    const int wave = t >> 6;       // 0..3 : rows [wave*32, wave*32+32)
    const int lane = t & 63;
    const int m16  = lane & 15;
    const int quad = lane >> 4;    // 0..3

    f32x4 acc[2][8];
    #pragma unroll
    for (int mt = 0; mt < 2; ++mt)
        #pragma unroll
        for (int nt = 0; nt < 8; ++nt)
            acc[mt][nt] = (f32x4){0.f, 0.f, 0.f, 0.f};

    const int arow0 = wave * 32 + m16;

    for (int kh = 0; kh < 2; ++kh) {
        const int k0 = kh * 64;
        // --- stage A half: 128 rows x 64 bf16 = 1024 chunks of 8, 4/thread ---
        #pragma unroll
        for (int i = 0; i < 4; ++i) {
            int c   = t + 256 * i;     // 0..1023
            int row = c >> 3;          // 8 chunks per row
            int off = c & 7;           // in 8-bf16 units
            int gr  = n0 + row;
            uint4 u = make_uint4(0, 0, 0, 0);
            if (gr < NPTS) {
                const float* src = x + (size_t)gr * CIN + k0 + off * 8;
                float4 f0 = *(const float4*)(src);
                float4 f1 = *(const float4*)(src + 4);
                u.x = (uint)f2bf(f0.x) | ((uint)f2bf(f0.y) << 16);
                u.y = (uint)f2bf(f0.z) | ((uint)f2bf(f0.w) << 16);
                u.z = (uint)f2bf(f1.x) | ((uint)f2bf(f1.y) << 16);
                u.w = (uint)f2bf(f1.z) | ((uint)f2bf(f1.w) << 16);
            }
            *(uint4*)&As[row * LDK + off * 8] = u;
        }
        // --- stage B half transposed: Bs[o][kl] = W[k0+kl][o]; 2048 f4, 8/thread
        #pragma unroll
        for (int i = 0; i < 8; ++i) {
            int fidx = t + 256 * i;    // 0..2047
            int kl   = fidx >> 5;      // 0..63
            int o4   = fidx & 31;
            float4 w = *(const float4*)(W + (size_t)(k0 + kl) * OC + o4 * 4);
            Bs[(o4 * 4 + 0) * LDK + kl] = f2bf(w.x);
            Bs[(o4 * 4 + 1) * LDK + kl] = f2bf(w.y);
            Bs[(o4 * 4 + 2) * LDK + kl] = f2bf(w.z);
            Bs[(o4 * 4 + 3) * LDK + kl] = f2bf(w.w);
        }
        __syncthreads();

        #pragma unroll
        for (int ks = 0; ks < 2; ++ks) {
            const int kb = ks * 32 + quad * 8;
            bf16x8 a0 = *(const bf16x8*)&As[(arow0 +  0) * LDK + kb];
            bf16x8 a1 = *(const bf16x8*)&As[(arow0 + 16) * LDK + kb];
            #pragma unroll
            for (int nt = 0; nt < 8; ++nt) {
                bf16x8 b = *(const bf16x8*)&Bs[(nt * 16 + m16) * LDK + kb];
                acc[0][nt] = __builtin_amdgcn_mfma_f32_16x16x32_bf16(a0, b, acc[0][nt], 0, 0, 0);
                acc[1][nt] = __builtin_amdgcn_mfma_f32_16x16x32_bf16(a1, b, acc[1][nt], 0, 0, 0);
            }
        }
        __syncthreads();
    }

    // --- epilogue ---
    #pragma unroll
    for (int mt = 0; mt < 2; ++mt) {
        #pragma unroll
        for (int nt = 0; nt < 8; ++nt) {
            const int col = nt * 16 + m16;
            const float bcol = bias[col];
            #pragma unroll
            for (int r = 0; r < 4; ++r) {
                int row = n0 + wave * 32 + mt * 16 + quad * 4 + r;
                if (row < NPTS) {
                    float v = acc[mt][nt][r] + bcol;
                    if (mat == 0) {
                        yq[(size_t)row * OC + col] = v;
                    } else if (mat == 1) {
                        yk[(size_t)row * OC + col] = f2bf(v);
                    } else {
                        yv[(size_t)row * OC + col] = f2bf(v);
                    }
                }
            }
        }
    }
}

// ---------------------------------------------------------------------------
// Kernel 2: per-point attention. 2 points per block, 256 threads.
// Within a point: 128 threads = (s,h); thread owns the 16-wide head slice.
// NOTE round-4 fix: the s_rm staging guard previously caught tl=16..31 and
// wrote s_rm[-16..-1] (LDS OOB, clobbered s_t in the r3 layout). Guard now
// range-exact.
// ---------------------------------------------------------------------------
__global__ __launch_bounds__(256) void attn_kernel(
    const float* __restrict__ p, const int* __restrict__ idx,
    const float* __restrict__ xq, const ushort* __restrict__ xk, const ushort* __restrict__ xv,
    const float* __restrict__ Wp1, const float* __restrict__ bp1,
    const float* __restrict__ gp,  const float* __restrict__ betap,
    const float* __restrict__ Wp2, const float* __restrict__ bp2,
    const float* __restrict__ gw1, const float* __restrict__ betaw1,
    const float* __restrict__ Ww1, const float* __restrict__ bw1,
    const float* __restrict__ gw2, const float* __restrict__ betaw2,
    const float* __restrict__ Ww2, const float* __restrict__ bw2,
    float* __restrict__ out)
{
    const int t  = threadIdx.x;     // 0..255
    const int pi = t >> 7;          // local point 0/1
    const int tl = t & 127;
    const int n  = blockIdx.x * 2 + pi;
    const int s  = tl >> 3;         // neighbor
    const int h  = tl & 7;          // head

    __shared__ float s_t[2][NS][4];
    __shared__ float s_rm[OSH + 1];
    __shared__ float s_logit[2][NS][NH];
    __shared__ float s_mx[2][NH];
    __shared__ float s_inv[2][NH];
    __shared__ float s_contrib[2][NS][OC];  // 16 KB

    if (tl < NS) {
        int ss = tl;
        int j = idx[n * NS + ss];
        float pr0 = p[j * 3 + 0] - p[n * 3 + 0];
        float pr1 = p[j * 3 + 1] - p[n * 3 + 1];
        float pr2 = p[j * 3 + 2] - p[n * 3 + 2];
        float u[3];
        #pragma unroll
        for (int c = 0; c < 3; ++c)
            u[c] = bp1[c] + pr0 * Wp1[0 * 3 + c] + pr1 * Wp1[1 * 3 + c] + pr2 * Wp1[2 * 3 + c];
        float m   = (u[0] + u[1] + u[2]) * (1.f / 3.f);
        float d0 = u[0] - m, d1 = u[1] - m, d2 = u[2] - m;
        float var = (d0 * d0 + d1 * d1 + d2 * d2) * (1.f / 3.f);
        float inv = rsqrtf(var + EPSF);
        #pragma unroll
        for (int c = 0; c < 3; ++c)
            s_t[pi][ss][c] = fmaxf((u[c] - m) * inv * gp[c] + betap[c], 0.f);
    } else if (pi == 0 && tl >= 32 && tl < 48) {
        int d = tl - 32;             // 0..15
        float acc = 0.f;
        #pragma unroll
        for (int o2 = 0; o2 < OSH; ++o2) acc += Ww2[d * OSH + o2];
        s_rm[d] = acc * (1.f / OSH);
    } else if (pi == 0 && tl == 48) {
        float acc = 0.f;
        #pragma unroll
        for (int o2 = 0; o2 < OSH; ++o2) acc += bw2[o2];
        s_rm[OSH] = acc * (1.f / OSH);
    }
    __syncthreads();

    const int j = idx[n * NS + s];
    const float t0 = s_t[pi][s][0], t1 = s_t[pi][s][1], t2 = s_t[pi][s][2];
    const int obase = h * DH;

    // pe for this head slice
    float pe[DH];
    #pragma unroll
    for (int d = 0; d < DH; ++d) {
        int o = obase + d;
        pe[d] = bp2[o] + t0 * Wp2[0 * OC + o] + t1 * Wp2[1 * OC + o] + t2 * Wp2[2 * OC + o];
    }

    // gather k,v (bf16) and build r = kg + pe - xq
    float vv[DH], r[DH];
    {
        const uint4* k4 = (const uint4*)(xk + (size_t)j * OC + obase);
        const uint4* v4 = (const uint4*)(xv + (size_t)j * OC + obase);
        const float4* q4 = (const float4*)(xq + (size_t)n * OC + obase);
        uint4 ku0 = k4[0], ku1 = k4[1];
        uint4 vu0 = v4[0], vu1 = v4[1];
        float kf[DH];
        bf2f2(ku0.x, kf[0], kf[1]);   bf2f2(ku0.y, kf[2], kf[3]);
        bf2f2(ku0.z, kf[4], kf[5]);   bf2f2(ku0.w, kf[6], kf[7]);
        bf2f2(ku1.x, kf[8], kf[9]);   bf2f2(ku1.y, kf[10], kf[11]);
        bf2f2(ku1.z, kf[12], kf[13]); bf2f2(ku1.w, kf[14], kf[15]);
        bf2f2(vu0.x, vv[0], vv[1]);   bf2f2(vu0.y, vv[2], vv[3]);
        bf2f2(vu0.z, vv[4], vv[5]);   bf2f2(vu0.w, vv[6], vv[7]);
        bf2f2(vu1.x, vv[8], vv[9]);   bf2f2(vu1.y, vv[10], vv[11]);
        bf2f2(vu1.z, vv[12], vv[13]); bf2f2(vu1.w, vv[14], vv[15]);
        #pragma unroll
        for (int q = 0; q < 4; ++q) {
            float4 qq = q4[q];
            r[q * 4 + 0] = kf[q * 4 + 0] + pe[q * 4 + 0] - qq.x;
            r[q * 4 + 1] = kf[q * 4 + 1] + pe[q * 4 + 1] - qq.y;
            r[q * 4 + 2] = kf[q * 4 + 2] + pe[q * 4 + 2] - qq.z;
            r[q * 4 + 3] = kf[q * 4 + 3] + pe[q * 4 + 3] - qq.w;
        }
    }

    // LN over D=16 + relu
    float a[DH];
    {
        float m = 0.f;
        #pragma unroll
        for (int d = 0; d < DH; ++d) m += r[d];
        m *= (1.f / DH);
        float var = 0.f;
        #pragma unroll
        for (int d = 0; d < DH; ++d) { float dd = r[d] - m; var += dd * dd; }
        var *= (1.f / DH);
        float inv = rsqrtf(var + EPSF);
        #pragma unroll
        for (int d = 0; d < DH; ++d)
            a[d] = fmaxf((r[d] - m) * inv * gw1[d] + betaw1[d], 0.f);
    }

    // w1 = a @ Ww1 + bw1
    float w1[OSH];
    #pragma unroll
    for (int o2 = 0; o2 < OSH; ++o2) w1[o2] = bw1[o2];
    #pragma unroll
    for (int d = 0; d < DH; ++d) {
        float av = a[d];
        #pragma unroll
        for (int o2 = 0; o2 < OSH; ++o2) w1[o2] = fmaf(av, Ww1[d * OSH + o2], w1[o2]);
    }

    // LN over OS=16 + relu, fused (@Ww2 + bw2).mean(-1)
    float logit;
    {
        float m = 0.f;
        #pragma unroll
        for (int o2 = 0; o2 < OSH; ++o2) m += w1[o2];
        m *= (1.f / OSH);
        float var = 0.f;
        #pragma unroll
        for (int o2 = 0; o2 < OSH; ++o2) { float dd = w1[o2] - m; var += dd * dd; }
        var *= (1.f / OSH);
        float inv = rsqrtf(var + EPSF);
        logit = s_rm[OSH];
        #pragma unroll
        for (int o2 = 0; o2 < OSH; ++o2) {
            float bv2 = fmaxf((w1[o2] - m) * inv * gw2[o2] + betaw2[o2], 0.f);
            logit = fmaf(bv2, s_rm[o2], logit);
        }
    }

    s_logit[pi][s][h] = logit;
    __syncthreads();

    if (tl < NH) {
        float mx = -1e30f;
        #pragma unroll
        for (int ss = 0; ss < NS; ++ss) mx = fmaxf(mx, s_logit[pi][ss][tl]);
        float denom = 0.f;
        #pragma unroll
        for (int ss = 0; ss < NS; ++ss) denom += __expf(s_logit[pi][ss][tl] - mx);
        s_mx[pi][tl] = mx;
        s_inv[pi][tl] = 1.f / denom;
    }
    __syncthreads();

    float w = __expf(logit - s_mx[pi][h]) * s_inv[pi][h];

    #pragma unroll
    for (int d = 0; d < DH; ++d)
        s_contrib[pi][s][obase + d] = (vv[d] + pe[d]) * w;
    __syncthreads();

    float acc = 0.f;
    #pragma unroll
    for (int ss = 0; ss < NS; ++ss) acc += s_contrib[pi][ss][tl];
    out[(size_t)n * OC + tl] = acc;
}

// ---------------------------------------------------------------------------
extern "C" void kernel_launch(void* const* d_in, const int* in_sizes, int n_in,
                              void* d_out, int out_size, void* d_ws, size_t ws_size,
                              hipStream_t stream) {
    const float* p     = (const float*)d_in[0];
    const float* x     = (const float*)d_in[1];
    const int*   idx   = (const int*)d_in[2];
    const float* Wq    = (const float*)d_in[3];
    const float* bq    = (const float*)d_in[4];
    const float* Wk    = (const float*)d_in[5];
    const float* bk    = (const float*)d_in[6];
    const float* Wv    = (const float*)d_in[7];
    const float* bv    = (const float*)d_in[8];
    const float* Wp1   = (const float*)d_in[9];
    const float* bp1   = (const float*)d_in[10];
    const float* gp    = (const float*)d_in[11];
    const float* betap = (const float*)d_in[12];
    const float* Wp2   = (const float*)d_in[13];
    const float* bp2   = (const float*)d_in[14];
    const float* gw1   = (const float*)d_in[15];
    const float* betaw1= (const float*)d_in[16];
    const float* Ww1   = (const float*)d_in[17];
    const float* bw1   = (const float*)d_in[18];
    const float* gw2   = (const float*)d_in[19];
    const float* betaw2= (const float*)d_in[20];
    const float* Ww2   = (const float*)d_in[21];
    const float* bw2   = (const float*)d_in[22];
    float* out = (float*)d_out;

    float*  xq = (float*)d_ws;                       // N*128 fp32
    ushort* xk = (ushort*)(xq + (size_t)NPTS * OC);  // N*128 bf16
    ushort* xv = xk + (size_t)NPTS * OC;             // N*128 bf16

    dim3 g1((NPTS + 127) / 128, 3);   // 235 x 3
    qkv_mfma<<<g1, 256, 0, stream>>>(x, Wq, Wk, Wv, bq, bk, bv, xq, xk, xv);

    attn_kernel<<<NPTS / 2, 256, 0, stream>>>(p, idx, xq, xk, xv,
                                              Wp1, bp1, gp, betap, Wp2, bp2,
                                              gw1, betaw1, Ww1, bw1,
                                              gw2, betaw2, Ww2, bw2, out);
}

// Round 7
// 225.739 us; speedup vs baseline: 1.0733x; 1.0733x over previous
//
#include <hip/hip_runtime.h>
#include <math.h>

typedef unsigned int  uint;
typedef unsigned short ushort;

// Problem constants
constexpr int NPTS = 30000;
constexpr int CIN  = 128;
constexpr int OC   = 128;   // O
constexpr int NH   = 8;     // heads
constexpr int NS   = 16;    // neighbors
constexpr int DH   = 16;    // O/H
constexpr int OSH  = 16;    // O/SHARE
constexpr float EPSF = 1e-5f;

typedef __attribute__((ext_vector_type(8))) short bf16x8;
typedef __attribute__((ext_vector_type(4))) float f32x4;
typedef __attribute__((ext_vector_type(2))) __fp16 h16x2;   // builtin-native half2

__device__ __forceinline__ ushort f2bf(float f) {
    uint u = __float_as_uint(f);
    u += 0x7fff + ((u >> 16) & 1);   // RNE
    return (ushort)(u >> 16);
}
__device__ __forceinline__ void bf2f2(uint u, float& f0, float& f1) {
    f0 = __uint_as_float(u << 16);
    f1 = __uint_as_float(u & 0xffff0000u);
}

#if defined(__has_builtin)
#if __has_builtin(__builtin_amdgcn_fdot2)
#define HAVE_FDOT2 1
#endif
#endif

// ---------------------------------------------------------------------------
// Kernel 1: QKV projection via bf16 MFMA (16x16x32).
// Block = 128 rows x 128 cols; K=128 in two 64-wide staged halves.
// All outputs bf16. Block (0, mat=0) additionally precomputes:
//   Ww1p[128] : Ww1 packed to f16 pairs, layout [d2][o2], d2 = d/2
//   rmean[17] : rowmean(Ww2), [16] = mean(bw2)
// ---------------------------------------------------------------------------
constexpr int LDK = 72;   // ushort stride for 64-k tiles (144 B, 16B-aligned)

__global__ __launch_bounds__(256) void qkv_mfma(
    const float* __restrict__ x,
    const float* __restrict__ Wq, const float* __restrict__ Wk, const float* __restrict__ Wv,
    const float* __restrict__ bq, const float* __restrict__ bk, const float* __restrict__ bv,
    const float* __restrict__ Ww1, const float* __restrict__ Ww2, const float* __restrict__ bw2,
    ushort* __restrict__ yq, ushort* __restrict__ yk, ushort* __restrict__ yv,
    uint* __restrict__ Ww1p, float* __restrict__ rmean)
{
    const int mat = blockIdx.y;
    const float* W    = (mat == 0) ? Wq : (mat == 1 ? Wk : Wv);
    const float* bias = (mat == 0) ? bq : (mat == 1 ? bk : bv);
    ushort* y         = (mat == 0) ? yq : (mat == 1 ? yk : yv);

    const int n0 = blockIdx.x * 128;
    const int t  = threadIdx.x;

    // --- one-block prep for attn (packed Ww1, rowmean Ww2) ---
    if (blockIdx.x == 0 && mat == 0) {
        if (t < 128) {
            int d2 = t >> 4, o2 = t & 15;
            h16x2 pk = __builtin_amdgcn_cvt_pkrtz(Ww1[(2 * d2) * OSH + o2],
                                                  Ww1[(2 * d2 + 1) * OSH + o2]);
            Ww1p[t] = *(uint*)&pk;
        } else if (t >= 128 && t < 144) {
            int d = t - 128;
            float acc = 0.f;
            #pragma unroll
            for (int o2 = 0; o2 < OSH; ++o2) acc += Ww2[d * OSH + o2];
            rmean[d] = acc * (1.f / OSH);
        } else if (t == 144) {
            float acc = 0.f;
            #pragma unroll
            for (int o2 = 0; o2 < OSH; ++o2) acc += bw2[o2];
            rmean[OSH] = acc * (1.f / OSH);
        }
    }

    __shared__ ushort As[128 * LDK];   // rows x k-half
    __shared__ ushort Bs[128 * LDK];   // cols x k-half (W^T)

    const int wave = t >> 6;       // 0..3 : rows [wave*32, wave*32+32)
    const int lane = t & 63;
    const int m16  = lane & 15;
    const int quad = lane >> 4;    // 0..3

    f32x4 acc[2][8];
    #pragma unroll
    for (int mt = 0; mt < 2; ++mt)
        #pragma unroll
        for (int nt = 0; nt < 8; ++nt)
            acc[mt][nt] = (f32x4){0.f, 0.f, 0.f, 0.f};

    const int arow0 = wave * 32 + m16;

    for (int kh = 0; kh < 2; ++kh) {
        const int k0 = kh * 64;
        #pragma unroll
        for (int i = 0; i < 4; ++i) {
            int c   = t + 256 * i;     // 0..1023
            int row = c >> 3;
            int off = c & 7;           // in 8-bf16 units
            int gr  = n0 + row;
            uint4 u = make_uint4(0, 0, 0, 0);
            if (gr < NPTS) {
                const float* src = x + (size_t)gr * CIN + k0 + off * 8;
                float4 f0 = *(const float4*)(src);
                float4 f1 = *(const float4*)(src + 4);
                u.x = (uint)f2bf(f0.x) | ((uint)f2bf(f0.y) << 16);
                u.y = (uint)f2bf(f0.z) | ((uint)f2bf(f0.w) << 16);
                u.z = (uint)f2bf(f1.x) | ((uint)f2bf(f1.y) << 16);
                u.w = (uint)f2bf(f1.z) | ((uint)f2bf(f1.w) << 16);
            }
            *(uint4*)&As[row * LDK + off * 8] = u;
        }
        #pragma unroll
        for (int i = 0; i < 8; ++i) {
            int fidx = t + 256 * i;    // 0..2047
            int kl   = fidx >> 5;      // 0..63
            int o4   = fidx & 31;
            float4 w = *(const float4*)(W + (size_t)(k0 + kl) * OC + o4 * 4);
            Bs[(o4 * 4 + 0) * LDK + kl] = f2bf(w.x);
            Bs[(o4 * 4 + 1) * LDK + kl] = f2bf(w.y);
            Bs[(o4 * 4 + 2) * LDK + kl] = f2bf(w.z);
            Bs[(o4 * 4 + 3) * LDK + kl] = f2bf(w.w);
        }
        __syncthreads();

        #pragma unroll
        for (int ks = 0; ks < 2; ++ks) {
            const int kb = ks * 32 + quad * 8;
            bf16x8 a0 = *(const bf16x8*)&As[(arow0 +  0) * LDK + kb];
            bf16x8 a1 = *(const bf16x8*)&As[(arow0 + 16) * LDK + kb];
            #pragma unroll
            for (int nt = 0; nt < 8; ++nt) {
                bf16x8 b = *(const bf16x8*)&Bs[(nt * 16 + m16) * LDK + kb];
                acc[0][nt] = __builtin_amdgcn_mfma_f32_16x16x32_bf16(a0, b, acc[0][nt], 0, 0, 0);
                acc[1][nt] = __builtin_amdgcn_mfma_f32_16x16x32_bf16(a1, b, acc[1][nt], 0, 0, 0);
            }
        }
        __syncthreads();
    }

    #pragma unroll
    for (int mt = 0; mt < 2; ++mt) {
        #pragma unroll
        for (int nt = 0; nt < 8; ++nt) {
            const int col = nt * 16 + m16;
            const float bcol = bias[col];
            #pragma unroll
            for (int r = 0; r < 4; ++r) {
                int row = n0 + wave * 32 + mt * 16 + quad * 4 + r;
                if (row < NPTS)
                    y[(size_t)row * OC + col] = f2bf(acc[mt][nt][r] + bcol);
            }
        }
    }
}

// ---------------------------------------------------------------------------
// Kernel 2: per-point attention. 1 point per block, 128 threads = (s,h).
// q/k/v all bf16. w1 matvec via v_dot2_f32_f16 with SGPR-resident packed Ww1.
// ---------------------------------------------------------------------------
__global__ __launch_bounds__(128) void attn_kernel(
    const float* __restrict__ p, const int* __restrict__ idx,
    const ushort* __restrict__ xq, const ushort* __restrict__ xk, const ushort* __restrict__ xv,
    const float* __restrict__ Wp1, const float* __restrict__ bp1,
    const float* __restrict__ gp,  const float* __restrict__ betap,
    const float* __restrict__ Wp2, const float* __restrict__ bp2,
    const float* __restrict__ gw1, const float* __restrict__ betaw1,
    const float* __restrict__ Ww1, const float* __restrict__ bw1,
    const float* __restrict__ gw2, const float* __restrict__ betaw2,
    const uint* __restrict__ Ww1p, const float* __restrict__ rmean,
    float* __restrict__ out)
{
    const int n = blockIdx.x;
    const int t = threadIdx.x;   // 0..127
    const int s = t >> 3;        // neighbor
    const int h = t & 7;         // head

    __shared__ float s_t[NS][4];
    __shared__ float s_logit[NS][NH];
    __shared__ float s_mx[NH];
    __shared__ float s_inv[NH];
    __shared__ float s_contrib[NS][OC]; // 8 KB

    if (t < NS) {
        int ss = t;
        int j = idx[n * NS + ss];
        float pr0 = p[j * 3 + 0] - p[n * 3 + 0];
        float pr1 = p[j * 3 + 1] - p[n * 3 + 1];
        float pr2 = p[j * 3 + 2] - p[n * 3 + 2];
        float u[3];
        #pragma unroll
        for (int c = 0; c < 3; ++c)
            u[c] = bp1[c] + pr0 * Wp1[0 * 3 + c] + pr1 * Wp1[1 * 3 + c] + pr2 * Wp1[2 * 3 + c];
        float m   = (u[0] + u[1] + u[2]) * (1.f / 3.f);
        float d0 = u[0] - m, d1 = u[1] - m, d2 = u[2] - m;
        float var = (d0 * d0 + d1 * d1 + d2 * d2) * (1.f / 3.f);
        float inv = rsqrtf(var + EPSF);
        #pragma unroll
        for (int c = 0; c < 3; ++c)
            s_t[ss][c] = fmaxf((u[c] - m) * inv * gp[c] + betap[c], 0.f);
    }
    __syncthreads();

    const int j = idx[n * NS + s];
    const float t0 = s_t[s][0], t1 = s_t[s][1], t2 = s_t[s][2];
    const int obase = h * DH;

    // pe for this head slice
    float pe[DH];
    #pragma unroll
    for (int d = 0; d < DH; ++d) {
        int o = obase + d;
        pe[d] = bp2[o] + t0 * Wp2[0 * OC + o] + t1 * Wp2[1 * OC + o] + t2 * Wp2[2 * OC + o];
    }

    // gather q,k,v (bf16) and build r = kg + pe - xq
    float vv[DH], r[DH];
    {
        const uint4* k4 = (const uint4*)(xk + (size_t)j * OC + obase);
        const uint4* v4 = (const uint4*)(xv + (size_t)j * OC + obase);
        const uint4* q4 = (const uint4*)(xq + (size_t)n * OC + obase);
        uint4 ku0 = k4[0], ku1 = k4[1];
        uint4 vu0 = v4[0], vu1 = v4[1];
        uint4 qu0 = q4[0], qu1 = q4[1];
        float kf[DH], qf[DH];
        bf2f2(ku0.x, kf[0], kf[1]);   bf2f2(ku0.y, kf[2], kf[3]);
        bf2f2(ku0.z, kf[4], kf[5]);   bf2f2(ku0.w, kf[6], kf[7]);
        bf2f2(ku1.x, kf[8], kf[9]);   bf2f2(ku1.y, kf[10], kf[11]);
        bf2f2(ku1.z, kf[12], kf[13]); bf2f2(ku1.w, kf[14], kf[15]);
        bf2f2(vu0.x, vv[0], vv[1]);   bf2f2(vu0.y, vv[2], vv[3]);
        bf2f2(vu0.z, vv[4], vv[5]);   bf2f2(vu0.w, vv[6], vv[7]);
        bf2f2(vu1.x, vv[8], vv[9]);   bf2f2(vu1.y, vv[10], vv[11]);
        bf2f2(vu1.z, vv[12], vv[13]); bf2f2(vu1.w, vv[14], vv[15]);
        bf2f2(qu0.x, qf[0], qf[1]);   bf2f2(qu0.y, qf[2], qf[3]);
        bf2f2(qu0.z, qf[4], qf[5]);   bf2f2(qu0.w, qf[6], qf[7]);
        bf2f2(qu1.x, qf[8], qf[9]);   bf2f2(qu1.y, qf[10], qf[11]);
        bf2f2(qu1.z, qf[12], qf[13]); bf2f2(qu1.w, qf[14], qf[15]);
        #pragma unroll
        for (int d = 0; d < DH; ++d)
            r[d] = kf[d] + pe[d] - qf[d];
    }

    // LN over D=16 + relu
    float a[DH];
    {
        float m = 0.f;
        #pragma unroll
        for (int d = 0; d < DH; ++d) m += r[d];
        m *= (1.f / DH);
        float var = 0.f;
        #pragma unroll
        for (int d = 0; d < DH; ++d) { float dd = r[d] - m; var += dd * dd; }
        var *= (1.f / DH);
        float inv = rsqrtf(var + EPSF);
        #pragma unroll
        for (int d = 0; d < DH; ++d)
            a[d] = fmaxf((r[d] - m) * inv * gw1[d] + betaw1[d], 0.f);
    }

    // w1 = a @ Ww1 + bw1
    float w1[OSH];
    #pragma unroll
    for (int o2 = 0; o2 < OSH; ++o2) w1[o2] = bw1[o2];
#ifdef HAVE_FDOT2
    {
        h16x2 ap[8];
        #pragma unroll
        for (int d2 = 0; d2 < 8; ++d2)
            ap[d2] = __builtin_amdgcn_cvt_pkrtz(a[2 * d2], a[2 * d2 + 1]);
        #pragma unroll
        for (int d2 = 0; d2 < 8; ++d2) {
            #pragma unroll
            for (int o2 = 0; o2 < OSH; ++o2) {
                uint wp = Ww1p[d2 * OSH + o2];   // uniform -> SGPR
                w1[o2] = __builtin_amdgcn_fdot2(ap[d2], *(h16x2*)&wp, w1[o2], false);
            }
        }
    }
#else
    #pragma unroll
    for (int d = 0; d < DH; ++d) {
        float av = a[d];
        #pragma unroll
        for (int o2 = 0; o2 < OSH; ++o2) w1[o2] = fmaf(av, Ww1[d * OSH + o2], w1[o2]);
    }
#endif

    // LN over OS=16 + relu, fused (@Ww2 + bw2).mean(-1) via rowmean
    float logit;
    {
        float m = 0.f;
        #pragma unroll
        for (int o2 = 0; o2 < OSH; ++o2) m += w1[o2];
        m *= (1.f / OSH);
        float var = 0.f;
        #pragma unroll
        for (int o2 = 0; o2 < OSH; ++o2) { float dd = w1[o2] - m; var += dd * dd; }
        var *= (1.f / OSH);
        float inv = rsqrtf(var + EPSF);
        logit = rmean[OSH];
        #pragma unroll
        for (int o2 = 0; o2 < OSH; ++o2) {
            float bv2 = fmaxf((w1[o2] - m) * inv * gw2[o2] + betaw2[o2], 0.f);
            logit = fmaf(bv2, rmean[o2], logit);
        }
    }

    s_logit[s][h] = logit;
    __syncthreads();

    if (t < NH) {
        float mx = -1e30f;
        #pragma unroll
        for (int ss = 0; ss < NS; ++ss) mx = fmaxf(mx, s_logit[ss][t]);
        float denom = 0.f;
        #pragma unroll
        for (int ss = 0; ss < NS; ++ss) denom += __expf(s_logit[ss][t] - mx);
        s_mx[t] = mx;
        s_inv[t] = 1.f / denom;
    }
    __syncthreads();

    float w = __expf(logit - s_mx[h]) * s_inv[h];

    #pragma unroll
    for (int d = 0; d < DH; ++d)
        s_contrib[s][obase + d] = (vv[d] + pe[d]) * w;
    __syncthreads();

    float acc = 0.f;
    #pragma unroll
    for (int ss = 0; ss < NS; ++ss) acc += s_contrib[ss][t];
    out[(size_t)n * OC + t] = acc;
}

// ---------------------------------------------------------------------------
extern "C" void kernel_launch(void* const* d_in, const int* in_sizes, int n_in,
                              void* d_out, int out_size, void* d_ws, size_t ws_size,
                              hipStream_t stream) {
    const float* p     = (const float*)d_in[0];
    const float* x     = (const float*)d_in[1];
    const int*   idx   = (const int*)d_in[2];
    const float* Wq    = (const float*)d_in[3];
    const float* bq    = (const float*)d_in[4];
    const float* Wk    = (const float*)d_in[5];
    const float* bk    = (const float*)d_in[6];
    const float* Wv    = (const float*)d_in[7];
    const float* bv    = (const float*)d_in[8];
    const float* Wp1   = (const float*)d_in[9];
    const float* bp1   = (const float*)d_in[10];
    const float* gp    = (const float*)d_in[11];
    const float* betap = (const float*)d_in[12];
    const float* Wp2   = (const float*)d_in[13];
    const float* bp2   = (const float*)d_in[14];
    const float* gw1   = (const float*)d_in[15];
    const float* betaw1= (const float*)d_in[16];
    const float* Ww1   = (const float*)d_in[17];
    const float* bw1   = (const float*)d_in[18];
    const float* gw2   = (const float*)d_in[19];
    const float* betaw2= (const float*)d_in[20];
    const float* Ww2   = (const float*)d_in[21];
    const float* bw2   = (const float*)d_in[22];
    float* out = (float*)d_out;

    // workspace: xq, xk, xv as bf16 (N*128 each), then prep data
    ushort* xq = (ushort*)d_ws;
    ushort* xk = xq + (size_t)NPTS * OC;
    ushort* xv = xk + (size_t)NPTS * OC;
    uint*   Ww1p  = (uint*)(xv + (size_t)NPTS * OC);   // 128 uints
    float*  rmean = (float*)(Ww1p + 128);              // 17 floats

    dim3 g1((NPTS + 127) / 128, 3);   // 235 x 3
    qkv_mfma<<<g1, 256, 0, stream>>>(x, Wq, Wk, Wv, bq, bk, bv,
                                     Ww1, Ww2, bw2,
                                     xq, xk, xv, Ww1p, rmean);

    attn_kernel<<<NPTS, 128, 0, stream>>>(p, idx, xq, xk, xv,
                                          Wp1, bp1, gp, betap, Wp2, bp2,
                                          gw1, betaw1, Ww1, bw1,
                                          gw2, betaw2, Ww1p, rmean, out);
}

// Round 8
// 223.295 us; speedup vs baseline: 1.0850x; 1.0109x over previous
//
#include <hip/hip_runtime.h>
#include <math.h>

typedef unsigned int  uint;
typedef unsigned short ushort;

// Problem constants
constexpr int NPTS = 30000;
constexpr int NPAD = 30080;  // 235 * 128, padded row count for tail-safe frag loads
constexpr int CIN  = 128;
constexpr int OC   = 128;   // O
constexpr int NH   = 8;     // heads
constexpr int NS   = 16;    // neighbors
constexpr int DH   = 16;    // O/H
constexpr int OSH  = 16;    // O/SHARE
constexpr float EPSF = 1e-5f;

typedef __attribute__((ext_vector_type(8))) short bf16x8;
typedef __attribute__((ext_vector_type(4))) float f32x4;
typedef __attribute__((ext_vector_type(2))) __fp16 h16x2;   // builtin-native half2

__device__ __forceinline__ ushort f2bf(float f) {
    uint u = __float_as_uint(f);
    u += 0x7fff + ((u >> 16) & 1);   // RNE
    return (ushort)(u >> 16);
}
__device__ __forceinline__ void bf2f2(uint u, float& f0, float& f1) {
    f0 = __uint_as_float(u << 16);
    f1 = __uint_as_float(u & 0xffff0000u);
}

#if defined(__has_builtin)
#if __has_builtin(__builtin_amdgcn_fdot2)
#define HAVE_FDOT2 1
#endif
#endif

// ---------------------------------------------------------------------------
// Kernel 0: prep. Blocks [0, 3760): x fp32 -> bf16 (rows >= NPTS zero-filled).
// Blocks 3760..3762: W{q,k,v} -> bf16 transposed WT[o][k] = W[k][o].
// Block 3763: Ww1 packed f16 pairs + rowmean(Ww2)/mean(bw2).
// ---------------------------------------------------------------------------
constexpr int XB_BLOCKS = (NPAD * CIN / 4) / 256;   // 3760

__global__ __launch_bounds__(256) void prep_kernel(
    const float* __restrict__ x,
    const float* __restrict__ Wq, const float* __restrict__ Wk, const float* __restrict__ Wv,
    const float* __restrict__ Ww1, const float* __restrict__ Ww2, const float* __restrict__ bw2,
    ushort* __restrict__ xb, ushort* __restrict__ WT,
    uint* __restrict__ Ww1p, float* __restrict__ rmean)
{
    const int b = blockIdx.x;
    const int t = threadIdx.x;
    if (b < XB_BLOCKS) {
        int e   = (b * 256 + t) * 4;       // element index
        int row = e >> 7;
        uint2 o = make_uint2(0, 0);
        if (row < NPTS) {
            float4 f = *(const float4*)(x + e);
            o.x = (uint)f2bf(f.x) | ((uint)f2bf(f.y) << 16);
            o.y = (uint)f2bf(f.z) | ((uint)f2bf(f.w) << 16);
        }
        *(uint2*)(xb + e) = o;
    } else if (b < XB_BLOCKS + 3) {
        int mat = b - XB_BLOCKS;
        const float* W = (mat == 0) ? Wq : (mat == 1 ? Wk : Wv);
        ushort* T = WT + mat * OC * CIN;
        if (t < OC) {
            // thread owns output col o = t; reads coalesced across threads
            for (int k = 0; k < CIN; ++k)
                T[t * CIN + k] = f2bf(W[k * OC + t]);
        }
    } else {
        if (t < 128) {
            int d2 = t >> 4, o2 = t & 15;
            h16x2 pk = __builtin_amdgcn_cvt_pkrtz(Ww1[(2 * d2) * OSH + o2],
                                                  Ww1[(2 * d2 + 1) * OSH + o2]);
            Ww1p[t] = *(uint*)&pk;
        } else if (t >= 128 && t < 144) {
            int d = t - 128;
            float acc = 0.f;
            #pragma unroll
            for (int o2 = 0; o2 < OSH; ++o2) acc += Ww2[d * OSH + o2];
            rmean[d] = acc * (1.f / OSH);
        } else if (t == 144) {
            float acc = 0.f;
            #pragma unroll
            for (int o2 = 0; o2 < OSH; ++o2) acc += bw2[o2];
            rmean[OSH] = acc * (1.f / OSH);
        }
    }
}

// ---------------------------------------------------------------------------
// Kernel 1: QKV projection via bf16 MFMA (16x16x32), staging-free.
// A/B fragments loaded directly from pre-converted global bf16 (xb, WT).
// No LDS. Per wave: 8 A-loads + 32 B-loads (b128) : 64 MFMAs.
// Fragments (m89/m91): A[m=lane&15][k=quad*8+j]; B[k][n] via WT rows;
// C/D col=lane&15, row=quad*4+reg.
// ---------------------------------------------------------------------------
__global__ __launch_bounds__(256) void qkv_mfma(
    const ushort* __restrict__ xb, const ushort* __restrict__ WT,
    const float* __restrict__ bq, const float* __restrict__ bk, const float* __restrict__ bv,
    ushort* __restrict__ yq, ushort* __restrict__ yk, ushort* __restrict__ yv)
{
    const int mat = blockIdx.y;
    const float* bias = (mat == 0) ? bq : (mat == 1 ? bk : bv);
    ushort* y         = (mat == 0) ? yq : (mat == 1 ? yk : yv);
    const ushort* T   = WT + mat * OC * CIN;

    const int n0   = blockIdx.x * 128;
    const int t    = threadIdx.x;
    const int wave = t >> 6;
    const int lane = t & 63;
    const int m16  = lane & 15;
    const int quad = lane >> 4;

    f32x4 acc[2][8];
    #pragma unroll
    for (int mt = 0; mt < 2; ++mt)
        #pragma unroll
        for (int nt = 0; nt < 8; ++nt)
            acc[mt][nt] = (f32x4){0.f, 0.f, 0.f, 0.f};

    const ushort* arow0 = xb + (size_t)(n0 + wave * 32 + m16) * CIN;       // rows < NPAD: safe
    const ushort* arow1 = arow0 + 16 * CIN;

    #pragma unroll
    for (int ks = 0; ks < 4; ++ks) {
        const int kb = ks * 32 + quad * 8;
        bf16x8 a0 = *(const bf16x8*)(arow0 + kb);
        bf16x8 a1 = *(const bf16x8*)(arow1 + kb);
        #pragma unroll
        for (int nt = 0; nt < 8; ++nt) {
            bf16x8 bfr = *(const bf16x8*)(T + (size_t)(nt * 16 + m16) * CIN + kb);
            acc[0][nt] = __builtin_amdgcn_mfma_f32_16x16x32_bf16(a0, bfr, acc[0][nt], 0, 0, 0);
            acc[1][nt] = __builtin_amdgcn_mfma_f32_16x16x32_bf16(a1, bfr, acc[1][nt], 0, 0, 0);
        }
    }

    #pragma unroll
    for (int mt = 0; mt < 2; ++mt) {
        #pragma unroll
        for (int nt = 0; nt < 8; ++nt) {
            const int col = nt * 16 + m16;
            const float bcol = bias[col];
            #pragma unroll
            for (int r = 0; r < 4; ++r) {
                int row = n0 + wave * 32 + mt * 16 + quad * 4 + r;
                if (row < NPTS)
                    y[(size_t)row * OC + col] = f2bf(acc[mt][nt][r] + bcol);
            }
        }
    }
}

// ---------------------------------------------------------------------------
// Kernel 2: per-point attention. 1 point per block, 128 threads = (s,h).
// q/k/v bf16. w1 matvec via v_dot2_f32_f16 with SGPR-resident packed Ww1.
// s_contrib padded to stride 132 floats (cuts contrib-write bank conflicts).
// ---------------------------------------------------------------------------
__global__ __launch_bounds__(128) void attn_kernel(
    const float* __restrict__ p, const int* __restrict__ idx,
    const ushort* __restrict__ xq, const ushort* __restrict__ xk, const ushort* __restrict__ xv,
    const float* __restrict__ Wp1, const float* __restrict__ bp1,
    const float* __restrict__ gp,  const float* __restrict__ betap,
    const float* __restrict__ Wp2, const float* __restrict__ bp2,
    const float* __restrict__ gw1, const float* __restrict__ betaw1,
    const float* __restrict__ Ww1, const float* __restrict__ bw1,
    const float* __restrict__ gw2, const float* __restrict__ betaw2,
    const uint* __restrict__ Ww1p, const float* __restrict__ rmean,
    float* __restrict__ out)
{
    const int n = blockIdx.x;
    const int t = threadIdx.x;   // 0..127
    const int s = t >> 3;        // neighbor
    const int h = t & 7;         // head

    __shared__ float s_t[NS][4];
    __shared__ float s_logit[NS][NH];
    __shared__ float s_mx[NH];
    __shared__ float s_inv[NH];
    __shared__ float s_contrib[NS][OC + 4];   // stride 132: 4-way max conflicts

    if (t < NS) {
        int ss = t;
        int j = idx[n * NS + ss];
        float pr0 = p[j * 3 + 0] - p[n * 3 + 0];
        float pr1 = p[j * 3 + 1] - p[n * 3 + 1];
        float pr2 = p[j * 3 + 2] - p[n * 3 + 2];
        float u[3];
        #pragma unroll
        for (int c = 0; c < 3; ++c)
            u[c] = bp1[c] + pr0 * Wp1[0 * 3 + c] + pr1 * Wp1[1 * 3 + c] + pr2 * Wp1[2 * 3 + c];
        float m   = (u[0] + u[1] + u[2]) * (1.f / 3.f);
        float d0 = u[0] - m, d1 = u[1] - m, d2 = u[2] - m;
        float var = (d0 * d0 + d1 * d1 + d2 * d2) * (1.f / 3.f);
        float inv = rsqrtf(var + EPSF);
        #pragma unroll
        for (int c = 0; c < 3; ++c)
            s_t[ss][c] = fmaxf((u[c] - m) * inv * gp[c] + betap[c], 0.f);
    }
    __syncthreads();

    const int j = idx[n * NS + s];
    const float t0 = s_t[s][0], t1 = s_t[s][1], t2 = s_t[s][2];
    const int obase = h * DH;

    // pe for this head slice — explicit float4 weight loads
    float pe[DH];
    {
        const float* W0 = Wp2 + obase;
        const float* W1 = Wp2 + OC + obase;
        const float* W2 = Wp2 + 2 * OC + obase;
        const float* B  = bp2 + obase;
        #pragma unroll
        for (int q = 0; q < 4; ++q) {
            float4 a0 = *(const float4*)(W0 + q * 4);
            float4 a1 = *(const float4*)(W1 + q * 4);
            float4 a2 = *(const float4*)(W2 + q * 4);
            float4 bb = *(const float4*)(B + q * 4);
            pe[q * 4 + 0] = bb.x + t0 * a0.x + t1 * a1.x + t2 * a2.x;
            pe[q * 4 + 1] = bb.y + t0 * a0.y + t1 * a1.y + t2 * a2.y;
            pe[q * 4 + 2] = bb.z + t0 * a0.z + t1 * a1.z + t2 * a2.z;
            pe[q * 4 + 3] = bb.w + t0 * a0.w + t1 * a1.w + t2 * a2.w;
        }
    }

    // gather q,k,v (bf16) and build r = kg + pe - xq
    float vv[DH], r[DH];
    {
        const uint4* k4 = (const uint4*)(xk + (size_t)j * OC + obase);
        const uint4* v4 = (const uint4*)(xv + (size_t)j * OC + obase);
        const uint4* q4 = (const uint4*)(xq + (size_t)n * OC + obase);
        uint4 ku0 = k4[0], ku1 = k4[1];
        uint4 vu0 = v4[0], vu1 = v4[1];
        uint4 qu0 = q4[0], qu1 = q4[1];
        float kf[DH], qf[DH];
        bf2f2(ku0.x, kf[0], kf[1]);   bf2f2(ku0.y, kf[2], kf[3]);
        bf2f2(ku0.z, kf[4], kf[5]);   bf2f2(ku0.w, kf[6], kf[7]);
        bf2f2(ku1.x, kf[8], kf[9]);   bf2f2(ku1.y, kf[10], kf[11]);
        bf2f2(ku1.z, kf[12], kf[13]); bf2f2(ku1.w, kf[14], kf[15]);
        bf2f2(vu0.x, vv[0], vv[1]);   bf2f2(vu0.y, vv[2], vv[3]);
        bf2f2(vu0.z, vv[4], vv[5]);   bf2f2(vu0.w, vv[6], vv[7]);
        bf2f2(vu1.x, vv[8], vv[9]);   bf2f2(vu1.y, vv[10], vv[11]);
        bf2f2(vu1.z, vv[12], vv[13]); bf2f2(vu1.w, vv[14], vv[15]);
        bf2f2(qu0.x, qf[0], qf[1]);   bf2f2(qu0.y, qf[2], qf[3]);
        bf2f2(qu0.z, qf[4], qf[5]);   bf2f2(qu0.w, qf[6], qf[7]);
        bf2f2(qu1.x, qf[8], qf[9]);   bf2f2(qu1.y, qf[10], qf[11]);
        bf2f2(qu1.z, qf[12], qf[13]); bf2f2(qu1.w, qf[14], qf[15]);
        #pragma unroll
        for (int d = 0; d < DH; ++d)
            r[d] = kf[d] + pe[d] - qf[d];
    }

    // LN over D=16 + relu
    float a[DH];
    {
        float m = 0.f;
        #pragma unroll
        for (int d = 0; d < DH; ++d) m += r[d];
        m *= (1.f / DH);
        float var = 0.f;
        #pragma unroll
        for (int d = 0; d < DH; ++d) { float dd = r[d] - m; var += dd * dd; }
        var *= (1.f / DH);
        float inv = rsqrtf(var + EPSF);
        #pragma unroll
        for (int d = 0; d < DH; ++d)
            a[d] = fmaxf((r[d] - m) * inv * gw1[d] + betaw1[d], 0.f);
    }

    // w1 = a @ Ww1 + bw1
    float w1[OSH];
    #pragma unroll
    for (int o2 = 0; o2 < OSH; ++o2) w1[o2] = bw1[o2];
#ifdef HAVE_FDOT2
    {
        h16x2 ap[8];
        #pragma unroll
        for (int d2 = 0; d2 < 8; ++d2)
            ap[d2] = __builtin_amdgcn_cvt_pkrtz(a[2 * d2], a[2 * d2 + 1]);
        #pragma unroll
        for (int d2 = 0; d2 < 8; ++d2) {
            #pragma unroll
            for (int o2 = 0; o2 < OSH; ++o2) {
                uint wp = Ww1p[d2 * OSH + o2];   // uniform -> SGPR
                w1[o2] = __builtin_amdgcn_fdot2(ap[d2], *(h16x2*)&wp, w1[o2], false);
            }
        }
    }
#else
    #pragma unroll
    for (int d = 0; d < DH; ++d) {
        float av = a[d];
        #pragma unroll
        for (int o2 = 0; o2 < OSH; ++o2) w1[o2] = fmaf(av, Ww1[d * OSH + o2], w1[o2]);
    }
#endif

    // LN over OS=16 + relu, fused (@Ww2 + bw2).mean(-1) via rowmean
    float logit;
    {
        float m = 0.f;
        #pragma unroll
        for (int o2 = 0; o2 < OSH; ++o2) m += w1[o2];
        m *= (1.f / OSH);
        float var = 0.f;
        #pragma unroll
        for (int o2 = 0; o2 < OSH; ++o2) { float dd = w1[o2] - m; var += dd * dd; }
        var *= (1.f / OSH);
        float inv = rsqrtf(var + EPSF);
        logit = rmean[OSH];
        #pragma unroll
        for (int o2 = 0; o2 < OSH; ++o2) {
            float bv2 = fmaxf((w1[o2] - m) * inv * gw2[o2] + betaw2[o2], 0.f);
            logit = fmaf(bv2, rmean[o2], logit);
        }
    }

    s_logit[s][h] = logit;
    __syncthreads();

    if (t < NH) {
        float mx = -1e30f;
        #pragma unroll
        for (int ss = 0; ss < NS; ++ss) mx = fmaxf(mx, s_logit[ss][t]);
        float denom = 0.f;
        #pragma unroll
        for (int ss = 0; ss < NS; ++ss) denom += __expf(s_logit[ss][t] - mx);
        s_mx[t] = mx;
        s_inv[t] = 1.f / denom;
    }
    __syncthreads();

    float w = __expf(logit - s_mx[h]) * s_inv[h];

    #pragma unroll
    for (int d = 0; d < DH; ++d)
        s_contrib[s][obase + d] = (vv[d] + pe[d]) * w;
    __syncthreads();

    float acc = 0.f;
    #pragma unroll
    for (int ss = 0; ss < NS; ++ss) acc += s_contrib[ss][t];
    out[(size_t)n * OC + t] = acc;
}

// ---------------------------------------------------------------------------
extern "C" void kernel_launch(void* const* d_in, const int* in_sizes, int n_in,
                              void* d_out, int out_size, void* d_ws, size_t ws_size,
                              hipStream_t stream) {
    const float* p     = (const float*)d_in[0];
    const float* x     = (const float*)d_in[1];
    const int*   idx   = (const int*)d_in[2];
    const float* Wq    = (const float*)d_in[3];
    const float* bq    = (const float*)d_in[4];
    const float* Wk    = (const float*)d_in[5];
    const float* bk    = (const float*)d_in[6];
    const float* Wv    = (const float*)d_in[7];
    const float* bv    = (const float*)d_in[8];
    const float* Wp1   = (const float*)d_in[9];
    const float* bp1   = (const float*)d_in[10];
    const float* gp    = (const float*)d_in[11];
    const float* betap = (const float*)d_in[12];
    const float* Wp2   = (const float*)d_in[13];
    const float* bp2   = (const float*)d_in[14];
    const float* gw1   = (const float*)d_in[15];
    const float* betaw1= (const float*)d_in[16];
    const float* Ww1   = (const float*)d_in[17];
    const float* bw1   = (const float*)d_in[18];
    const float* gw2   = (const float*)d_in[19];
    const float* betaw2= (const float*)d_in[20];
    const float* Ww2   = (const float*)d_in[21];
    const float* bw2   = (const float*)d_in[22];
    float* out = (float*)d_out;

    // workspace layout (all 16B-aligned):
    ushort* xb = (ushort*)d_ws;                        // NPAD*128 bf16
    ushort* WT = xb + (size_t)NPAD * CIN;              // 3*128*128 bf16
    ushort* xq = WT + 3 * OC * CIN;                    // N*128 bf16
    ushort* xk = xq + (size_t)NPTS * OC;
    ushort* xv = xk + (size_t)NPTS * OC;
    uint*   Ww1p  = (uint*)(xv + (size_t)NPTS * OC);   // 128 uints
    float*  rmean = (float*)(Ww1p + 128);              // 17 floats

    prep_kernel<<<XB_BLOCKS + 4, 256, 0, stream>>>(x, Wq, Wk, Wv, Ww1, Ww2, bw2,
                                                   xb, WT, Ww1p, rmean);

    dim3 g1(NPAD / 128, 3);   // 235 x 3
    qkv_mfma<<<g1, 256, 0, stream>>>(xb, WT, bq, bk, bv, xq, xk, xv);

    attn_kernel<<<NPTS, 128, 0, stream>>>(p, idx, xq, xk, xv,
                                          Wp1, bp1, gp, betap, Wp2, bp2,
                                          gw1, betaw1, Ww1, bw1,
                                          gw2, betaw2, Ww1p, rmean, out);
}